// Round 1
// baseline (799.808 us; speedup 1.0000x reference)
//
#include <hip/hip_runtime.h>
#include <hip/hip_bf16.h>
#include <math.h>

typedef float f32x4 __attribute__((ext_vector_type(4)));
typedef short bf16x8 __attribute__((ext_vector_type(8)));

#define B_    128
#define NENC  2048
#define NCMD  512
#define D_    64
#define NF_   1024
#define H_    8
#define MHALF 32768   // D * NF/2
#define NCOL  65536   // 2*MHALF

// round-to-nearest-even fp32 -> bf16 (bit-level, 3 VALU ops)
__device__ __forceinline__ unsigned short f2bf(float f) {
  unsigned int u = __builtin_bit_cast(unsigned int, f);
  u += 0x7fffu + ((u >> 16) & 1u);
  return (unsigned short)(u >> 16);
}

__device__ __forceinline__ bf16x8 cvt8(f32x4 lo, f32x4 hi) {
  bf16x8 r;
  r[0] = (short)f2bf(lo[0]); r[1] = (short)f2bf(lo[1]);
  r[2] = (short)f2bf(lo[2]); r[3] = (short)f2bf(lo[3]);
  r[4] = (short)f2bf(hi[0]); r[5] = (short)f2bf(hi[1]);
  r[6] = (short)f2bf(hi[2]); r[7] = (short)f2bf(hi[3]);
  return r;
}

// ---------------------------------------------------------------------------
// Kernel A: y[b, nf, d] = LN_d( gelu( [feature@wz.T | hidden@wh.T] ) ), bf16 out
// Grid: 512 blocks (one per 128 output cols), 256 threads = 4 waves.
// Wave tile 64(b) x 64(col); MFMA 16x16x32 bf16; frags loaded DIRECT from
// global (fp32, 32B/lane contiguous) and converted in-register. No LDS/barriers.
// ---------------------------------------------------------------------------
__global__ __launch_bounds__(256, 2) void gemm_act_ln(
    const float* __restrict__ feat, const float* __restrict__ hid,
    const float* __restrict__ wz,   const float* __restrict__ wh,
    const float* __restrict__ lng,  const float* __restrict__ lnb,
    unsigned short* __restrict__ yws)
{
  const int col0 = blockIdx.x * 128;
  const float* Amat; const float* Wmat; int wr0;
  if (col0 < MHALF) { Amat = feat; Wmat = wz; wr0 = col0; }
  else              { Amat = hid;  Wmat = wh; wr0 = col0 - MHALF; }

  const int tid  = threadIdx.x;
  const int wave = tid >> 6, lane = tid & 63;
  const int quad = lane >> 4, l16 = lane & 15;
  const int rw = (wave & 1) * 64;     // batch-row offset of wave tile
  const int cw = (wave >> 1) * 64;    // col offset of wave tile

  const float* aptr = Amat + (size_t)(rw + l16) * NENC + quad * 8;
  const float* wptr = Wmat + (size_t)(wr0 + cw + l16) * NENC + quad * 8;

  f32x4 acc[4][4];
  #pragma unroll
  for (int mt = 0; mt < 4; ++mt)
    #pragma unroll
    for (int nt = 0; nt < 4; ++nt)
      acc[mt][nt] = (f32x4){0.f, 0.f, 0.f, 0.f};

  for (int k = 0; k < NENC; k += 32) {
    bf16x8 af[4], bfr[4];
    #pragma unroll
    for (int mt = 0; mt < 4; ++mt) {
      const float* p = aptr + (size_t)mt * 16 * NENC + k;
      af[mt] = cvt8(*(const f32x4*)p, *(const f32x4*)(p + 4));
    }
    #pragma unroll
    for (int nt = 0; nt < 4; ++nt) {
      const float* p = wptr + (size_t)nt * 16 * NENC + k;
      bfr[nt] = cvt8(*(const f32x4*)p, *(const f32x4*)(p + 4));
    }
    #pragma unroll
    for (int mt = 0; mt < 4; ++mt)
      #pragma unroll
      for (int nt = 0; nt < 4; ++nt)
        acc[mt][nt] = __builtin_amdgcn_mfma_f32_16x16x32_bf16(
            af[mt], bfr[nt], acc[mt][nt], 0, 0, 0);
  }

  // Epilogue: exact GELU, then LayerNorm over the 64 cols of this wave tile
  // (wave cols == exactly one nf-group). C-frag: col = l16+16*nt (=d),
  // row = quad*4+r (+16*mt) (=b).
  float gv[4], bv[4];
  #pragma unroll
  for (int nt = 0; nt < 4; ++nt) { int d = nt * 16 + l16; gv[nt] = lng[d]; bv[nt] = lnb[d]; }
  const int nf = (col0 + cw) >> 6;

  #pragma unroll
  for (int mt = 0; mt < 4; ++mt) {
    float g[4][4];  // [nt][r]
    #pragma unroll
    for (int nt = 0; nt < 4; ++nt)
      #pragma unroll
      for (int r = 0; r < 4; ++r) {
        float x = acc[mt][nt][r];
        g[nt][r] = 0.5f * x * (1.0f + erff(x * 0.70710678118654752f));
      }
    float s1[4], s2[4];
    #pragma unroll
    for (int r = 0; r < 4; ++r) {
      s1[r] = g[0][r] + g[1][r] + g[2][r] + g[3][r];
      s2[r] = g[0][r]*g[0][r] + g[1][r]*g[1][r] + g[2][r]*g[2][r] + g[3][r]*g[3][r];
    }
    #pragma unroll
    for (int msk = 1; msk < 16; msk <<= 1) {
      #pragma unroll
      for (int r = 0; r < 4; ++r) {
        s1[r] += __shfl_xor(s1[r], msk);
        s2[r] += __shfl_xor(s2[r], msk);
      }
    }
    #pragma unroll
    for (int r = 0; r < 4; ++r) {
      float mu  = s1[r] * (1.0f / 64.0f);
      float var = s2[r] * (1.0f / 64.0f) - mu * mu;
      float rs  = rsqrtf(var + 1e-5f);
      int brow = rw + mt * 16 + quad * 4 + r;
      size_t base = ((size_t)brow * NF_ + nf) * D_;
      #pragma unroll
      for (int nt = 0; nt < 4; ++nt) {
        int d = nt * 16 + l16;
        yws[base + d] = f2bf((g[nt][r] - mu) * rs * gv[nt] + bv[nt]);
      }
    }
  }
}

// ---------------------------------------------------------------------------
// Kernel C (tiny): Q[b, hd] = command[b] . q_w[hd], fp32
// ---------------------------------------------------------------------------
__global__ __launch_bounds__(256) void qproj(
    const float* __restrict__ cmd, const float* __restrict__ qw,
    float* __restrict__ qws)
{
  const int b = blockIdx.x;
  const int t = threadIdx.x;
  __shared__ float cs[NCMD];
  cs[t]       = cmd[b * NCMD + t];
  cs[t + 256] = cmd[b * NCMD + t + 256];
  __syncthreads();
  #pragma unroll
  for (int o = 0; o < 2; ++o) {
    int hd = t + o * 256;
    const float* wr = qw + (size_t)hd * NCMD;
    float s = 0.f;
    for (int k = 0; k < NCMD; k += 4) {
      f32x4 w4 = *(const f32x4*)(wr + k);
      s += w4[0]*cs[k] + w4[1]*cs[k+1] + w4[2]*cs[k+2] + w4[3]*cs[k+3];
    }
    qws[b * NCMD + hd] = s;
  }
}

// ---------------------------------------------------------------------------
// Kernel B: fused K/V projection + gated softmax attention, one WG per (b,h).
// 4 waves x 256 n-rows each, chunks of 16 rows. k_w/v_w head slices live in
// registers as MFMA B-frags; y rows stream as A-frags (already bf16).
// Online softmax with rescaled V-accumulator; no K/V materialization.
// ---------------------------------------------------------------------------
__global__ __launch_bounds__(256, 2) void attn(
    const unsigned short* __restrict__ yws, const float* __restrict__ qws,
    const float* __restrict__ kw, const float* __restrict__ vw,
    float* __restrict__ out)
{
  const int b = blockIdx.x >> 3, h = blockIdx.x & 7;
  const int tid  = threadIdx.x;
  const int wave = tid >> 6, lane = tid & 63;
  const int quad = lane >> 4, l16 = lane & 15;

  // persistent B-frags: B[k=e][n=d] = k_w[h*64+d][e] (row-major [512,64] fp32)
  bf16x8 kf[4][2], vf[4][2];
  #pragma unroll
  for (int dt = 0; dt < 4; ++dt)
    #pragma unroll
    for (int s = 0; s < 2; ++s) {
      size_t off = (size_t)((h * 64 + dt * 16 + l16) * 64 + s * 32 + quad * 8);
      const float* kp = kw + off;
      const float* vp = vw + off;
      kf[dt][s] = cvt8(*(const f32x4*)kp, *(const f32x4*)(kp + 4));
      vf[dt][s] = cvt8(*(const f32x4*)vp, *(const f32x4*)(vp + 4));
    }
  float qv[4];
  #pragma unroll
  for (int dt = 0; dt < 4; ++dt)
    qv[dt] = qws[b * 512 + h * 64 + dt * 16 + l16];

  const unsigned short* ybase = yws + (size_t)b * NF_ * D_;
  float m = -INFINITY, ssum = 0.f;
  float accS[4] = {0.f, 0.f, 0.f, 0.f};

  for (int c = 0; c < 16; ++c) {
    const int n0 = wave * 256 + c * 16;
    const unsigned short* yp = ybase + (size_t)(n0 + l16) * D_ + quad * 8;
    bf16x8 a0 = *(const bf16x8*)yp;          // k = 0..31
    bf16x8 a1 = *(const bf16x8*)(yp + 32);   // k = 32..63
    f32x4 aK[4], aV[4];
    #pragma unroll
    for (int dt = 0; dt < 4; ++dt) {
      f32x4 z = {0.f, 0.f, 0.f, 0.f};
      aK[dt] = __builtin_amdgcn_mfma_f32_16x16x32_bf16(a0, kf[dt][0], z,      0, 0, 0);
      aK[dt] = __builtin_amdgcn_mfma_f32_16x16x32_bf16(a1, kf[dt][1], aK[dt], 0, 0, 0);
      aV[dt] = __builtin_amdgcn_mfma_f32_16x16x32_bf16(a0, vf[dt][0], z,      0, 0, 0);
      aV[dt] = __builtin_amdgcn_mfma_f32_16x16x32_bf16(a1, vf[dt][1], aV[dt], 0, 0, 0);
    }
    // per-lane partials over its 4 d's; rows n = n0 + quad*4 + r
    float qk[4], av[4];
    #pragma unroll
    for (int r = 0; r < 4; ++r) {
      qk[r] = qv[0]*aK[0][r] + qv[1]*aK[1][r] + qv[2]*aK[2][r] + qv[3]*aK[3][r];
      av[r] = fabsf(aV[0][r]) + fabsf(aV[1][r]) + fabsf(aV[2][r]) + fabsf(aV[3][r]);
    }
    #pragma unroll
    for (int msk = 1; msk < 16; msk <<= 1) {
      #pragma unroll
      for (int r = 0; r < 4; ++r) {
        qk[r] += __shfl_xor(qk[r], msk);
        av[r] += __shfl_xor(av[r], msk);
      }
    }
    // logit = (sum|V|/64) * QK / sqrt(64) = av*qk/512
    float l0 = av[0] * qk[0] * 0.001953125f;
    float l1 = av[1] * qk[1] * 0.001953125f;
    float l2 = av[2] * qk[2] * 0.001953125f;
    float l3 = av[3] * qk[3] * 0.001953125f;
    float cm = fmaxf(fmaxf(l0, l1), fmaxf(l2, l3));
    float mn = fmaxf(m, cm);
    float sc = __expf(m - mn);   // first iter: exp(-inf)=0
    float w0 = __expf(l0 - mn), w1 = __expf(l1 - mn);
    float w2 = __expf(l2 - mn), w3 = __expf(l3 - mn);
    ssum = ssum * sc + (w0 + w1 + w2 + w3);
    #pragma unroll
    for (int dt = 0; dt < 4; ++dt)
      accS[dt] = accS[dt] * sc
               + w0*aV[dt][0] + w1*aV[dt][1] + w2*aV[dt][2] + w3*aV[dt][3];
    m = mn;
  }

  // combine the 4 quads of the wave (lanes L, L^16, L^32, L^48 share d)
  float Mw = m;
  Mw = fmaxf(Mw, __shfl_xor(Mw, 16));
  Mw = fmaxf(Mw, __shfl_xor(Mw, 32));
  float fac = __expf(m - Mw);
  ssum *= fac;
  #pragma unroll
  for (int dt = 0; dt < 4; ++dt) accS[dt] *= fac;
  ssum += __shfl_xor(ssum, 16); ssum += __shfl_xor(ssum, 32);
  #pragma unroll
  for (int dt = 0; dt < 4; ++dt) {
    accS[dt] += __shfl_xor(accS[dt], 16);
    accS[dt] += __shfl_xor(accS[dt], 32);
  }

  // combine the 4 waves via LDS
  __shared__ float sS[4][64];
  __shared__ float sM[4], sSum[4];
  if (lane < 16) {
    #pragma unroll
    for (int dt = 0; dt < 4; ++dt) sS[wave][dt * 16 + lane] = accS[dt];
    if (lane == 0) { sM[wave] = Mw; sSum[wave] = ssum; }
  }
  __syncthreads();
  if (tid < 64) {
    float M = fmaxf(fmaxf(sM[0], sM[1]), fmaxf(sM[2], sM[3]));
    float st = 0.f, val = 0.f;
    #pragma unroll
    for (int w = 0; w < 4; ++w) {
      float e = __expf(sM[w] - M);
      st  += sSum[w] * e;
      val += sS[w][tid] * e;
    }
    out[(size_t)(b * H_ + h) * D_ + tid] = val / st;
  }
}

extern "C" void kernel_launch(void* const* d_in, const int* in_sizes, int n_in,
                              void* d_out, int out_size, void* d_ws, size_t ws_size,
                              hipStream_t stream) {
  const float* feat = (const float*)d_in[0];
  const float* hid  = (const float*)d_in[1];
  const float* cmd  = (const float*)d_in[2];
  const float* wz   = (const float*)d_in[3];
  const float* wh   = (const float*)d_in[4];
  const float* qw   = (const float*)d_in[5];
  const float* kw   = (const float*)d_in[6];
  const float* vw   = (const float*)d_in[7];
  const float* lng  = (const float*)d_in[8];
  const float* lnb  = (const float*)d_in[9];
  float* out = (float*)d_out;

  unsigned short* yws = (unsigned short*)d_ws;                       // 16.78 MB bf16 y
  float* qws = (float*)((char*)d_ws + (size_t)B_ * NF_ * D_ * 2);    // 256 KB fp32 Q

  qproj<<<B_, 256, 0, stream>>>(cmd, qw, qws);
  gemm_act_ln<<<NCOL / 128, 256, 0, stream>>>(feat, hid, wz, wh, lng, lnb, yws);
  attn<<<B_ * H_, 256, 0, stream>>>(yws, qws, kw, vw, out);
}

// Round 3
// 627.463 us; speedup vs baseline: 1.2747x; 1.2747x over previous
//
#include <hip/hip_runtime.h>
#include <hip/hip_bf16.h>
#include <math.h>

typedef float f32x4 __attribute__((ext_vector_type(4)));
typedef short bf16x8 __attribute__((ext_vector_type(8)));

#define B_    128
#define NENC  2048
#define NCMD  512
#define D_    64
#define NF_   1024
#define H_    8
#define MHALF 32768   // D * NF/2
#define NCOL  65536   // 2*MHALF

// round-to-nearest-even fp32 -> bf16 (bit-level)
__device__ __forceinline__ unsigned short f2bf(float f) {
  unsigned int u = __builtin_bit_cast(unsigned int, f);
  u += 0x7fffu + ((u >> 16) & 1u);
  return (unsigned short)(u >> 16);
}

__device__ __forceinline__ bf16x8 cvt8(f32x4 lo, f32x4 hi) {
  bf16x8 r;
  r[0] = (short)f2bf(lo[0]); r[1] = (short)f2bf(lo[1]);
  r[2] = (short)f2bf(lo[2]); r[3] = (short)f2bf(lo[3]);
  r[4] = (short)f2bf(hi[0]); r[5] = (short)f2bf(hi[1]);
  r[6] = (short)f2bf(hi[2]); r[7] = (short)f2bf(hi[3]);
  return r;
}

// packed fp32x2 -> bf16x2 (v_cvt_pk_bf16_f32 on gfx950); memcpy instead of
// bit_cast because __hip_bfloat162 is not trivially copyable on this ROCm.
__device__ __forceinline__ int pkbf2(float a, float b) {
  __hip_bfloat162 t = __float22bfloat162_rn(float2{a, b});
  int r; __builtin_memcpy(&r, &t, 4); return r;
}

__device__ __forceinline__ bf16x8 cvt8v(f32x4 lo, f32x4 hi) {
  int4 r;
  r.x = pkbf2(lo[0], lo[1]);
  r.y = pkbf2(lo[2], lo[3]);
  r.z = pkbf2(hi[0], hi[1]);
  r.w = pkbf2(hi[2], hi[3]);
  bf16x8 o; __builtin_memcpy(&o, &r, 16); return o;
}

#define GLDS(gp, lp) __builtin_amdgcn_global_load_lds(                        \
    (const __attribute__((address_space(1))) unsigned int*)(gp),              \
    (__attribute__((address_space(3))) unsigned int*)(lp), 16, 0, 0)

// ---------------------------------------------------------------------------
// Kernel A: y[b, nf, d] = LN_d( gelu( [feature@wz.T | hidden@wh.T] ) ), bf16 out
// Grid: 512 blocks (128 output cols each), 256 threads = 4 waves.
// Block tile 128(b) x 128(col), BK=64 fp32 staged via async global_load_lds
// (fire-and-forget: no VGPR dests, full MLP regardless of register budget).
// LDS stores XOR-swizzled (cu ^ row&15 on the GLOBAL side, since the LDS dest
// of global_load_lds is lane-contiguous) so frag ds_read_b128s are 4-way max.
// Wave tile 64x64; MFMA 16x16x32 bf16; fp32->bf16 via packed cvt in-register.
// ---------------------------------------------------------------------------
__global__ __launch_bounds__(256, 2) void gemm_act_ln(
    const float* __restrict__ feat, const float* __restrict__ hid,
    const float* __restrict__ wz,   const float* __restrict__ wh,
    const float* __restrict__ lng,  const float* __restrict__ lnb,
    unsigned short* __restrict__ yws)
{
  const int col0 = blockIdx.x * 128;
  const float* Amat; const float* Wmat; int wr0;
  if (col0 < MHALF) { Amat = feat; Wmat = wz; wr0 = col0; }
  else              { Amat = hid;  Wmat = wh; wr0 = col0 - MHALF; }

  const int tid  = threadIdx.x;
  const int wave = tid >> 6, lane = tid & 63;
  const int quad = lane >> 4, l16 = lane & 15;
  const int rw = (wave & 1) * 64;     // batch-row offset of wave tile
  const int cw = (wave >> 1) * 64;    // col offset of wave tile

  // 64 KB LDS: [128 rows][16 units of 16B] each, unit-swizzled
  __shared__ float As[128 * 64];
  __shared__ float Ws[128 * 64];

  f32x4 acc[4][4];
  #pragma unroll
  for (int mt = 0; mt < 4; ++mt)
    #pragma unroll
    for (int nt = 0; nt < 4; ++nt)
      acc[mt][nt] = (f32x4){0.f, 0.f, 0.f, 0.f};

  // per-thread staging offsets (8 phases x 2 matrices)
  const int srow = tid >> 4;          // rows 0..15 per phase step of 16
  const int scu  = tid & 15;

  for (int kt = 0; kt < NENC; kt += 64) {
    // ---- async stage: tile [128 rows][64 floats] for A and W ----
    #pragma unroll
    for (int ph = 0; ph < 8; ++ph) {
      int row = ph * 16 + srow;                 // 0..127
      int gc  = (scu ^ (row & 15)) * 4;         // swizzled k-unit
      int s4  = (row * 16 + scu) * 4;           // LDS float index
      GLDS(Amat + (size_t)row * NENC + kt + gc, &As[s4]);
      GLDS(Wmat + (size_t)(wr0 + row) * NENC + kt + gc, &Ws[s4]);
    }
    __syncthreads();   // drains vmcnt -> LDS valid

    #pragma unroll
    for (int half = 0; half < 2; ++half) {
      const int ub = half * 8 + quad * 2;
      bf16x8 af[4], bfr[4];
      #pragma unroll
      for (int mt = 0; mt < 4; ++mt) {
        int r = rw + mt * 16 + l16;
        f32x4 lo = *(const f32x4*)&As[(r * 16 + ((ub)     ^ l16)) * 4];
        f32x4 hi = *(const f32x4*)&As[(r * 16 + ((ub + 1) ^ l16)) * 4];
        af[mt] = cvt8v(lo, hi);
      }
      #pragma unroll
      for (int nt = 0; nt < 4; ++nt) {
        int r = cw + nt * 16 + l16;
        f32x4 lo = *(const f32x4*)&Ws[(r * 16 + ((ub)     ^ l16)) * 4];
        f32x4 hi = *(const f32x4*)&Ws[(r * 16 + ((ub + 1) ^ l16)) * 4];
        bfr[nt] = cvt8v(lo, hi);
      }
      #pragma unroll
      for (int mt = 0; mt < 4; ++mt)
        #pragma unroll
        for (int nt = 0; nt < 4; ++nt)
          acc[mt][nt] = __builtin_amdgcn_mfma_f32_16x16x32_bf16(
              af[mt], bfr[nt], acc[mt][nt], 0, 0, 0);
    }
    __syncthreads();   // all waves done reading before next overwrite
  }

  // Epilogue: exact GELU, then LayerNorm over the 64 cols of this wave tile
  // (wave cols == exactly one nf-group). C-frag: col = l16+16*nt (=d),
  // row = quad*4+r (+16*mt) (=b).
  float gv[4], bv[4];
  #pragma unroll
  for (int nt = 0; nt < 4; ++nt) { int d = nt * 16 + l16; gv[nt] = lng[d]; bv[nt] = lnb[d]; }
  const int nf = (col0 + cw) >> 6;

  #pragma unroll
  for (int mt = 0; mt < 4; ++mt) {
    float g[4][4];  // [nt][r]
    #pragma unroll
    for (int nt = 0; nt < 4; ++nt)
      #pragma unroll
      for (int r = 0; r < 4; ++r) {
        float x = acc[mt][nt][r];
        g[nt][r] = 0.5f * x * (1.0f + erff(x * 0.70710678118654752f));
      }
    float s1[4], s2[4];
    #pragma unroll
    for (int r = 0; r < 4; ++r) {
      s1[r] = g[0][r] + g[1][r] + g[2][r] + g[3][r];
      s2[r] = g[0][r]*g[0][r] + g[1][r]*g[1][r] + g[2][r]*g[2][r] + g[3][r]*g[3][r];
    }
    #pragma unroll
    for (int msk = 1; msk < 16; msk <<= 1) {
      #pragma unroll
      for (int r = 0; r < 4; ++r) {
        s1[r] += __shfl_xor(s1[r], msk);
        s2[r] += __shfl_xor(s2[r], msk);
      }
    }
    #pragma unroll
    for (int r = 0; r < 4; ++r) {
      float mu  = s1[r] * (1.0f / 64.0f);
      float var = s2[r] * (1.0f / 64.0f) - mu * mu;
      float rs  = rsqrtf(var + 1e-5f);
      int brow = rw + mt * 16 + quad * 4 + r;
      size_t base = ((size_t)brow * NF_ + nf) * D_;
      #pragma unroll
      for (int nt = 0; nt < 4; ++nt) {
        int d = nt * 16 + l16;
        yws[base + d] = f2bf((g[nt][r] - mu) * rs * gv[nt] + bv[nt]);
      }
    }
  }
}

// ---------------------------------------------------------------------------
// Kernel C (tiny): Q[b, hd] = command[b] . q_w[hd], fp32
// Grid 256: block = (b, half); one output per thread.
// ---------------------------------------------------------------------------
__global__ __launch_bounds__(256) void qproj(
    const float* __restrict__ cmd, const float* __restrict__ qw,
    float* __restrict__ qws)
{
  const int b = blockIdx.x >> 1;
  const int hd0 = (blockIdx.x & 1) * 256;
  const int t = threadIdx.x;
  __shared__ float cs[NCMD];
  cs[t]       = cmd[b * NCMD + t];
  cs[t + 256] = cmd[b * NCMD + t + 256];
  __syncthreads();
  const int hd = hd0 + t;
  const float* wr = qw + (size_t)hd * NCMD;
  float s = 0.f;
  for (int k = 0; k < NCMD; k += 4) {
    f32x4 w4 = *(const f32x4*)(wr + k);
    s += w4[0]*cs[k] + w4[1]*cs[k+1] + w4[2]*cs[k+2] + w4[3]*cs[k+3];
  }
  qws[b * NCMD + hd] = s;
}

// ---------------------------------------------------------------------------
// Kernel B: fused K/V projection + gated softmax attention, one WG per (b,h).
// 4 waves x 256 n-rows each, chunks of 16 rows. k_w/v_w head slices live in
// registers as MFMA B-frags; y rows stream as A-frags (already bf16).
// Online softmax with rescaled V-accumulator; no K/V materialization.
// ---------------------------------------------------------------------------
__global__ __launch_bounds__(256, 2) void attn(
    const unsigned short* __restrict__ yws, const float* __restrict__ qws,
    const float* __restrict__ kw, const float* __restrict__ vw,
    float* __restrict__ out)
{
  const int b = blockIdx.x >> 3, h = blockIdx.x & 7;
  const int tid  = threadIdx.x;
  const int wave = tid >> 6, lane = tid & 63;
  const int quad = lane >> 4, l16 = lane & 15;

  // persistent B-frags: B[k=e][n=d] = k_w[h*64+d][e] (row-major [512,64] fp32)
  bf16x8 kf[4][2], vf[4][2];
  #pragma unroll
  for (int dt = 0; dt < 4; ++dt)
    #pragma unroll
    for (int s = 0; s < 2; ++s) {
      size_t off = (size_t)((h * 64 + dt * 16 + l16) * 64 + s * 32 + quad * 8);
      const float* kp = kw + off;
      const float* vp = vw + off;
      kf[dt][s] = cvt8(*(const f32x4*)kp, *(const f32x4*)(kp + 4));
      vf[dt][s] = cvt8(*(const f32x4*)vp, *(const f32x4*)(vp + 4));
    }
  float qv[4];
  #pragma unroll
  for (int dt = 0; dt < 4; ++dt)
    qv[dt] = qws[b * 512 + h * 64 + dt * 16 + l16];

  const unsigned short* ybase = yws + (size_t)b * NF_ * D_;
  float m = -INFINITY, ssum = 0.f;
  float accS[4] = {0.f, 0.f, 0.f, 0.f};

  for (int c = 0; c < 16; ++c) {
    const int n0 = wave * 256 + c * 16;
    const unsigned short* yp = ybase + (size_t)(n0 + l16) * D_ + quad * 8;
    bf16x8 a0 = *(const bf16x8*)yp;          // k = 0..31
    bf16x8 a1 = *(const bf16x8*)(yp + 32);   // k = 32..63
    f32x4 aK[4], aV[4];
    #pragma unroll
    for (int dt = 0; dt < 4; ++dt) {
      f32x4 z = {0.f, 0.f, 0.f, 0.f};
      aK[dt] = __builtin_amdgcn_mfma_f32_16x16x32_bf16(a0, kf[dt][0], z,      0, 0, 0);
      aK[dt] = __builtin_amdgcn_mfma_f32_16x16x32_bf16(a1, kf[dt][1], aK[dt], 0, 0, 0);
      aV[dt] = __builtin_amdgcn_mfma_f32_16x16x32_bf16(a0, vf[dt][0], z,      0, 0, 0);
      aV[dt] = __builtin_amdgcn_mfma_f32_16x16x32_bf16(a1, vf[dt][1], aV[dt], 0, 0, 0);
    }
    // per-lane partials over its 4 d's; rows n = n0 + quad*4 + r
    float qk[4], av[4];
    #pragma unroll
    for (int r = 0; r < 4; ++r) {
      qk[r] = qv[0]*aK[0][r] + qv[1]*aK[1][r] + qv[2]*aK[2][r] + qv[3]*aK[3][r];
      av[r] = fabsf(aV[0][r]) + fabsf(aV[1][r]) + fabsf(aV[2][r]) + fabsf(aV[3][r]);
    }
    #pragma unroll
    for (int msk = 1; msk < 16; msk <<= 1) {
      #pragma unroll
      for (int r = 0; r < 4; ++r) {
        qk[r] += __shfl_xor(qk[r], msk);
        av[r] += __shfl_xor(av[r], msk);
      }
    }
    // logit = (sum|V|/64) * QK / sqrt(64) = av*qk/512
    float l0 = av[0] * qk[0] * 0.001953125f;
    float l1 = av[1] * qk[1] * 0.001953125f;
    float l2 = av[2] * qk[2] * 0.001953125f;
    float l3 = av[3] * qk[3] * 0.001953125f;
    float cm = fmaxf(fmaxf(l0, l1), fmaxf(l2, l3));
    float mn = fmaxf(m, cm);
    float sc = __expf(m - mn);   // first iter: exp(-inf)=0
    float w0 = __expf(l0 - mn), w1 = __expf(l1 - mn);
    float w2 = __expf(l2 - mn), w3 = __expf(l3 - mn);
    ssum = ssum * sc + (w0 + w1 + w2 + w3);
    #pragma unroll
    for (int dt = 0; dt < 4; ++dt)
      accS[dt] = accS[dt] * sc
               + w0*aV[dt][0] + w1*aV[dt][1] + w2*aV[dt][2] + w3*aV[dt][3];
    m = mn;
  }

  // combine the 4 quads of the wave (lanes L, L^16, L^32, L^48 share d)
  float Mw = m;
  Mw = fmaxf(Mw, __shfl_xor(Mw, 16));
  Mw = fmaxf(Mw, __shfl_xor(Mw, 32));
  float fac = __expf(m - Mw);
  ssum *= fac;
  #pragma unroll
  for (int dt = 0; dt < 4; ++dt) accS[dt] *= fac;
  ssum += __shfl_xor(ssum, 16); ssum += __shfl_xor(ssum, 32);
  #pragma unroll
  for (int dt = 0; dt < 4; ++dt) {
    accS[dt] += __shfl_xor(accS[dt], 16);
    accS[dt] += __shfl_xor(accS[dt], 32);
  }

  // combine the 4 waves via LDS
  __shared__ float sS[4][64];
  __shared__ float sM[4], sSum[4];
  if (lane < 16) {
    #pragma unroll
    for (int dt = 0; dt < 4; ++dt) sS[wave][dt * 16 + lane] = accS[dt];
    if (lane == 0) { sM[wave] = Mw; sSum[wave] = ssum; }
  }
  __syncthreads();
  if (tid < 64) {
    float M = fmaxf(fmaxf(sM[0], sM[1]), fmaxf(sM[2], sM[3]));
    float st = 0.f, val = 0.f;
    #pragma unroll
    for (int w = 0; w < 4; ++w) {
      float e = __expf(sM[w] - M);
      st  += sSum[w] * e;
      val += sS[w][tid] * e;
    }
    out[(size_t)(b * H_ + h) * D_ + tid] = val / st;
  }
}

extern "C" void kernel_launch(void* const* d_in, const int* in_sizes, int n_in,
                              void* d_out, int out_size, void* d_ws, size_t ws_size,
                              hipStream_t stream) {
  const float* feat = (const float*)d_in[0];
  const float* hid  = (const float*)d_in[1];
  const float* cmd  = (const float*)d_in[2];
  const float* wz   = (const float*)d_in[3];
  const float* wh   = (const float*)d_in[4];
  const float* qw   = (const float*)d_in[5];
  const float* kw   = (const float*)d_in[6];
  const float* vw   = (const float*)d_in[7];
  const float* lng  = (const float*)d_in[8];
  const float* lnb  = (const float*)d_in[9];
  float* out = (float*)d_out;

  unsigned short* yws = (unsigned short*)d_ws;                       // 16.78 MB bf16 y
  float* qws = (float*)((char*)d_ws + (size_t)B_ * NF_ * D_ * 2);    // 256 KB fp32 Q

  qproj<<<2 * B_, 256, 0, stream>>>(cmd, qw, qws);
  gemm_act_ln<<<NCOL / 128, 256, 0, stream>>>(feat, hid, wz, wh, lng, lnb, yws);
  attn<<<B_ * H_, 256, 0, stream>>>(yws, qws, kw, vw, out);
}